// Round 8
// baseline (82.867 us; speedup 1.0000x reference)
//
#include <hip/hip_runtime.h>

#define NW 10
typedef float f32x2 __attribute__((ext_vector_type(2)));

// ---- VOP3P packed fp32 helpers (compiler won't form these on its own) ----
__device__ __forceinline__ f32x2 pk_mul(f32x2 a, f32x2 b) {
    f32x2 d;
    asm("v_pk_mul_f32 %0, %1, %2" : "=v"(d) : "v"(a), "v"(b));
    return d;
}
__device__ __forceinline__ f32x2 pk_fma(f32x2 a, f32x2 b, f32x2 c) {
    f32x2 d;
    asm("v_pk_fma_f32 %0, %1, %2, %3" : "=v"(d) : "v"(a), "v"(b), "v"(c));
    return d;
}
// d = a * swap2(b) + c   (swap folded into op_sel on src1)
__device__ __forceinline__ f32x2 pk_fma_sw1(f32x2 a, f32x2 b, f32x2 c) {
    f32x2 d;
    asm("v_pk_fma_f32 %0, %1, %2, %3 op_sel:[0,1,0] op_sel_hi:[1,0,1]"
        : "=v"(d) : "v"(a), "v"(b), "v"(c));
    return d;
}
__device__ __forceinline__ f32x2 sp2(float x)           { return f32x2{ x,  x}; }
__device__ __forceinline__ f32x2 sp2pm(float x)         { return f32x2{ x, -x}; }
__device__ __forceinline__ f32x2 sp2mp(float x)         { return f32x2{-x,  x}; }

// CNOT-ring fused permutation: psi_final[i] = psi_in[gperm(i)].
// Linear over GF(2): gperm(a^b) = gperm(a)^gperm(b).
__device__ __forceinline__ int gperm(int v) {
    #pragma unroll
    for (int k = 9; k >= 0; --k) {
        const int cs = 9 - k;                 // control bit (qubit k)
        const int ts = 9 - ((k + 1) % NW);    // target bit (qubit (k+1)%10)
        v ^= ((v >> cs) & 1) << ts;
    }
    return v;
}

// Two-level padded float index (R3-proven): scalar trip sides 2-way (free),
// vector sides at bandwidth floor; 16B alignment kept (pad terms %4==0).
__device__ __forceinline__ int PF(int i) {
    return i + ((i >> 5) << 2) + ((i >> 8) << 3);
}
#define PBUF 1176   // max PF(1023) = 1171

// readlane: broadcast lane value -> wave-uniform (SGPR)
__device__ __forceinline__ float rl(float v, int lane) {
    return __int_as_float(__builtin_amdgcn_readlane(__float_as_int(v), lane));
}

// ---- packed complex gate [[a,b],[-conj(b),conj(a)]], f32x2 distance D ----
template<int D>
__device__ __forceinline__ void cgv(f32x2* rf, f32x2* mf,
                                    float ar, float ai, float br, float bi) {
    const f32x2 sAr = sp2(ar),  sAi  = sp2(ai),  sAiN = sp2(-ai);
    const f32x2 sBr = sp2(br),  sBrN = sp2(-br);
    const f32x2 sBi = sp2(bi),  sBiN = sp2(-bi);
    #pragma unroll
    for (int base = 0; base < 8; base += 2 * D) {
        #pragma unroll
        for (int off = 0; off < D; ++off) {
            const int j0 = base + off, j1 = j0 + D;
            const f32x2 v0r = rf[j0], v0i = mf[j0];
            const f32x2 v1r = rf[j1], v1i = mf[j1];
            // n0r = ar*v0r - ai*v0i + br*v1r - bi*v1i
            f32x2 t = pk_mul(sAr, v0r);
            t = pk_fma(sAiN, v0i, t); t = pk_fma(sBr, v1r, t);
            rf[j0] = pk_fma(sBiN, v1i, t);
            // n0i = ar*v0i + ai*v0r + br*v1i + bi*v1r
            t = pk_mul(sAr, v0i);
            t = pk_fma(sAi, v0r, t);  t = pk_fma(sBr, v1i, t);
            mf[j0] = pk_fma(sBi, v1r, t);
            // n1r = ar*v1r + ai*v1i - br*v0r - bi*v0i
            t = pk_mul(sAr, v1r);
            t = pk_fma(sAi, v1i, t);  t = pk_fma(sBrN, v0r, t);
            rf[j1] = pk_fma(sBiN, v0i, t);
            // n1i = ar*v1i - ai*v1r - br*v0i + bi*v0r
            t = pk_mul(sAr, v1i);
            t = pk_fma(sAiN, v1r, t); t = pk_fma(sBrN, v0i, t);
            mf[j1] = pk_fma(sBi, v0r, t);
        }
    }
}

// packed complex gate WITHIN each f32x2 (R6-verified formulas, op_sel swaps)
__device__ __forceinline__ void cgv0(f32x2* rf, f32x2* mf,
                                     float ar, float ai, float br, float bi) {
    const f32x2 sAr  = sp2(ar);
    const f32x2 sAiN = sp2mp(ai);   // {-ai, ai}
    const f32x2 sAiP = sp2pm(ai);   // { ai,-ai}
    const f32x2 sBrN = sp2pm(br);   // { br,-br}
    const f32x2 sBiN = sp2(-bi);
    const f32x2 sBi  = sp2(bi);
    #pragma unroll
    for (int j = 0; j < 8; ++j) {
        const f32x2 vr = rf[j], vi = mf[j];
        // rf = ar*vr + aiN*vi + brN*swap(vr) - bi*swap(vi)
        f32x2 t = pk_mul(sAr, vr);
        t = pk_fma(sAiN, vi, t);
        t = pk_fma_sw1(sBrN, vr, t);
        rf[j] = pk_fma_sw1(sBiN, vi, t);
        // mf = ar*vi + aiP*vr + brN*swap(vi) + bi*swap(vr)
        t = pk_mul(sAr, vi);
        t = pk_fma(sAiP, vr, t);
        t = pk_fma_sw1(sBrN, vi, t);
        mf[j] = pk_fma_sw1(sBi, vr, t);
    }
}

// ---- packed real RY gate [[c,-s],[s,c]], f32x2 distance D ----
template<int D>
__device__ __forceinline__ void rgv(f32x2* rf, f32x2* mf, float c, float s) {
    const f32x2 sC = sp2(c), sS = sp2(s), sSN = sp2(-s);
    #pragma unroll
    for (int base = 0; base < 8; base += 2 * D) {
        #pragma unroll
        for (int off = 0; off < D; ++off) {
            const int j0 = base + off, j1 = j0 + D;
            const f32x2 v0r = rf[j0], v0i = mf[j0];
            const f32x2 v1r = rf[j1], v1i = mf[j1];
            rf[j0] = pk_fma(sSN, v1r, pk_mul(sC, v0r));
            mf[j0] = pk_fma(sSN, v1i, pk_mul(sC, v0i));
            rf[j1] = pk_fma(sC, v1r, pk_mul(sS, v0r));
            mf[j1] = pk_fma(sC, v1i, pk_mul(sS, v0i));
        }
    }
}

// packed real RY gate WITHIN each f32x2
__device__ __forceinline__ void rgv0(f32x2* rf, f32x2* mf, float c, float s) {
    const f32x2 sC = sp2(c), sSN = sp2mp(s);   // {-s, s}
    #pragma unroll
    for (int j = 0; j < 8; ++j) {
        const f32x2 vr = rf[j], vi = mf[j];
        rf[j] = pk_fma_sw1(sSN, vr, pk_mul(sC, vr));
        mf[j] = pk_fma_sw1(sSN, vi, pk_mul(sC, vi));
    }
}

// One wave (64 threads) per block = per state. 16 amps/lane as 8 f32x2 pairs.
// Layouts: L0: i = t<<4 | r;  L1: i = (t>>4)<<8 | r<<4 | (t&15);
//          L2: i = ((r>>2)&3)<<8 | t<<2 | (r&3).
__global__ __launch_bounds__(64) void qsa_main(
    const float* __restrict__ x,
    const float* __restrict__ rx0,
    const float* __restrict__ ry0,
    const float* __restrict__ ry1,
    float* __restrict__ out) {

    __shared__ __align__(16) float reb[PBUF];
    __shared__ __align__(16) float imb[PBUF];

    const int t = threadIdx.x;
    const int n = blockIdx.x;

    // ---- load row (L0 layout): rf[j] = amps (16t+2j, 16t+2j+1) ----
    f32x2 rf[8], mf[8];
    const float* xr = x + ((size_t)n << 10) + (t << 4);
    #pragma unroll
    for (int k = 0; k < 4; ++k) {
        const float4 v = *reinterpret_cast<const float4*>(xr + 4 * k);
        rf[2*k]   = f32x2{v.x, v.y};
        rf[2*k+1] = f32x2{v.z, v.w};
    }

    // ---- per-wire coefficients in lanes 0..9 ----
    float car = 0.f, cai = 0.f, cbr = 0.f, cbi = 0.f, cc1 = 0.f, cs1 = 0.f;
    if (t < NW) {
        float sx, cx, sy0, cy0;
        sincosf(0.5f * rx0[t], &sx,  &cx);
        sincosf(0.5f * ry0[t], &sy0, &cy0);
        sincosf(0.5f * ry1[t], &cs1, &cc1);
        car =  cy0 * cx;  cai =  sy0 * sx;   // fused RY(ry0)*RX(rx0)
        cbr = -sy0 * cx;  cbi = -cy0 * sx;
    }

    // ---- sum of squares -> normalization ----
    f32x2 ssv = {0.f, 0.f};
    #pragma unroll
    for (int j = 0; j < 8; ++j) ssv += rf[j] * rf[j];
    float ss = ssv.x + ssv.y;
    #pragma unroll
    for (int b = 32; b > 0; b >>= 1) ss += __shfl_xor(ss, b, 64);
    const float scale = 1.0f / fmaxf(sqrtf(ss), 1e-12f);

    // ========= layer 1, phase A (L0 bits 0-3 -> wires 9,8,7,6) =========
    {   // wire 9 (within-pair): input is real; fold in normalization
        const float ar = rl(car,9), ai = rl(cai,9), br = rl(cbr,9), bi = rl(cbi,9);
        const f32x2 sSc  = sp2(scale);
        const f32x2 sAr  = sp2(ar);
        const f32x2 sAiP = sp2pm(ai);   // { ai,-ai}
        const f32x2 sBrN = sp2pm(br);   // { br,-br}
        const f32x2 sBi  = sp2(bi);
        #pragma unroll
        for (int j = 0; j < 8; ++j) {
            const f32x2 v = pk_mul(sSc, rf[j]);
            rf[j] = pk_fma_sw1(sBrN, v, pk_mul(sAr, v));
            mf[j] = pk_fma_sw1(sBi,  v, pk_mul(sAiP, v));
        }
    }
    cgv<1>(rf, mf, rl(car,8), rl(cai,8), rl(cbr,8), rl(cbi,8));   // wire 8
    cgv<2>(rf, mf, rl(car,7), rl(cai,7), rl(cbr,7), rl(cbi,7));   // wire 7
    cgv<4>(rf, mf, rl(car,6), rl(cai,6), rl(cbr,6), rl(cbi,6));   // wire 6

    // T1: write L0 (b128 per plane), read L1 (b32 per plane)
    #pragma unroll
    for (int k = 0; k < 4; ++k) {
        const int p = PF((t << 4) + 4 * k);
        *reinterpret_cast<float4*>(&reb[p]) =
            make_float4(rf[2*k].x, rf[2*k].y, rf[2*k+1].x, rf[2*k+1].y);
        *reinterpret_cast<float4*>(&imb[p]) =
            make_float4(mf[2*k].x, mf[2*k].y, mf[2*k+1].x, mf[2*k+1].y);
    }
    __syncthreads();
    {
        const int b0 = ((t >> 4) << 8) | (t & 15);
        #pragma unroll
        for (int j = 0; j < 8; ++j) {
            const int p0 = PF(b0 + ((2*j) << 4)), p1 = PF(b0 + ((2*j+1) << 4));
            rf[j] = f32x2{reb[p0], reb[p1]};
            mf[j] = f32x2{imb[p0], imb[p1]};
        }
    }

    // ========= layer 1, phase B (L1 bits 4-7 -> wires 5,4,3,2) =========
    cgv0  (rf, mf, rl(car,5), rl(cai,5), rl(cbr,5), rl(cbi,5));   // wire 5
    cgv<1>(rf, mf, rl(car,4), rl(cai,4), rl(cbr,4), rl(cbi,4));   // wire 4
    cgv<2>(rf, mf, rl(car,3), rl(cai,3), rl(cbr,3), rl(cbi,3));   // wire 3
    cgv<4>(rf, mf, rl(car,2), rl(cai,2), rl(cbr,2), rl(cbi,2));   // wire 2

    // T2: write L1 (b32), read L2 (b128)
    __syncthreads();
    {
        const int b0 = ((t >> 4) << 8) | (t & 15);
        #pragma unroll
        for (int j = 0; j < 8; ++j) {
            const int p0 = PF(b0 + ((2*j) << 4)), p1 = PF(b0 + ((2*j+1) << 4));
            reb[p0] = rf[j].x; reb[p1] = rf[j].y;
            imb[p0] = mf[j].x; imb[p1] = mf[j].y;
        }
    }
    __syncthreads();
    #pragma unroll
    for (int k = 0; k < 4; ++k) {
        const int p = PF((k << 8) | (t << 2));
        const float4 qr = *reinterpret_cast<const float4*>(&reb[p]);
        const float4 qi = *reinterpret_cast<const float4*>(&imb[p]);
        rf[2*k] = f32x2{qr.x, qr.y}; rf[2*k+1] = f32x2{qr.z, qr.w};
        mf[2*k] = f32x2{qi.x, qi.y}; mf[2*k+1] = f32x2{qi.z, qi.w};
    }

    // ========= layer 1, phase C (L2: r bit2 -> wire 1, r bit3 -> wire 0) ====
    cgv<2>(rf, mf, rl(car,1), rl(cai,1), rl(cbr,1), rl(cbi,1));   // wire 1
    cgv<4>(rf, mf, rl(car,0), rl(cai,0), rl(cbr,0), rl(cbi,0));   // wire 0

    // T3: write L2 (b128), read CNOT-ring gather -> L0 (b32)
    __syncthreads();
    #pragma unroll
    for (int k = 0; k < 4; ++k) {
        const int p = PF((k << 8) | (t << 2));
        *reinterpret_cast<float4*>(&reb[p]) =
            make_float4(rf[2*k].x, rf[2*k].y, rf[2*k+1].x, rf[2*k+1].y);
        *reinterpret_cast<float4*>(&imb[p]) =
            make_float4(mf[2*k].x, mf[2*k].y, mf[2*k+1].x, mf[2*k+1].y);
    }
    __syncthreads();
    {
        const int gt = gperm(t << 4);
        #pragma unroll
        for (int j = 0; j < 8; ++j) {
            const int p0 = PF(gt ^ gperm(2*j)), p1 = PF(gt ^ gperm(2*j+1));
            rf[j] = f32x2{reb[p0], reb[p1]};
            mf[j] = f32x2{imb[p0], imb[p1]};
        }
    }

    // ========= layer 2, phase A2 (L0 -> wires 9,8,7,6) =========
    rgv0  (rf, mf, rl(cc1,9), rl(cs1,9));   // wire 9
    rgv<1>(rf, mf, rl(cc1,8), rl(cs1,8));   // wire 8
    rgv<2>(rf, mf, rl(cc1,7), rl(cs1,7));   // wire 7
    rgv<4>(rf, mf, rl(cc1,6), rl(cs1,6));   // wire 6

    // T4: write L0 (b128), read L1 (b32)
    __syncthreads();
    #pragma unroll
    for (int k = 0; k < 4; ++k) {
        const int p = PF((t << 4) + 4 * k);
        *reinterpret_cast<float4*>(&reb[p]) =
            make_float4(rf[2*k].x, rf[2*k].y, rf[2*k+1].x, rf[2*k+1].y);
        *reinterpret_cast<float4*>(&imb[p]) =
            make_float4(mf[2*k].x, mf[2*k].y, mf[2*k+1].x, mf[2*k+1].y);
    }
    __syncthreads();
    {
        const int b0 = ((t >> 4) << 8) | (t & 15);
        #pragma unroll
        for (int j = 0; j < 8; ++j) {
            const int p0 = PF(b0 + ((2*j) << 4)), p1 = PF(b0 + ((2*j+1) << 4));
            rf[j] = f32x2{reb[p0], reb[p1]};
            mf[j] = f32x2{imb[p0], imb[p1]};
        }
    }

    // ========= layer 2, phase B2 (L1 -> wires 5,4,3,2) =========
    rgv0  (rf, mf, rl(cc1,5), rl(cs1,5));   // wire 5
    rgv<1>(rf, mf, rl(cc1,4), rl(cs1,4));   // wire 4
    rgv<2>(rf, mf, rl(cc1,3), rl(cs1,3));   // wire 3
    rgv<4>(rf, mf, rl(cc1,2), rl(cs1,2));   // wire 2

    // T5: write L1 (b32), read L2 (b128)
    __syncthreads();
    {
        const int b0 = ((t >> 4) << 8) | (t & 15);
        #pragma unroll
        for (int j = 0; j < 8; ++j) {
            const int p0 = PF(b0 + ((2*j) << 4)), p1 = PF(b0 + ((2*j+1) << 4));
            reb[p0] = rf[j].x; reb[p1] = rf[j].y;
            imb[p0] = mf[j].x; imb[p1] = mf[j].y;
        }
    }
    __syncthreads();
    #pragma unroll
    for (int k = 0; k < 4; ++k) {
        const int p = PF((k << 8) | (t << 2));
        const float4 qr = *reinterpret_cast<const float4*>(&reb[p]);
        const float4 qi = *reinterpret_cast<const float4*>(&imb[p]);
        rf[2*k] = f32x2{qr.x, qr.y}; rf[2*k+1] = f32x2{qr.z, qr.w};
        mf[2*k] = f32x2{qi.x, qi.y}; mf[2*k+1] = f32x2{qi.z, qi.w};
    }

    // ========= layer 2, phase C2 (L2 -> wires 1,0) =========
    rgv<2>(rf, mf, rl(cc1,1), rl(cs1,1));   // wire 1
    rgv<4>(rf, mf, rl(cc1,0), rl(cs1,0));   // wire 0

    // ---- Z expectations (L2: amp r = 2j + pair-lane) ----
    f32x2 accP = {0,0}, acc9 = {0,0}, acc8 = {0,0}, acc1 = {0,0}, acc0 = {0,0};
    const f32x2 pm = {1.f, -1.f};
    #pragma unroll
    for (int j = 0; j < 8; ++j) {
        const f32x2 p = rf[j]*rf[j] + mf[j]*mf[j];
        accP += p;
        acc9 += pm * p;
        if (j & 1) acc8 -= p; else acc8 += p;
        if (j & 2) acc1 -= p; else acc1 += p;
        if (j & 4) acc0 -= p; else acc0 += p;
    }
    float P  = accP.x + accP.y;
    float a9 = acc9.x + acc9.y;
    float a8 = acc8.x + acc8.y;
    float a1 = acc1.x + acc1.y;
    float a0 = acc0.x + acc0.y;
    #pragma unroll
    for (int b = 1; b < 64; b <<= 1) {
        a0 += __shfl_xor(a0, b, 64);
        a1 += __shfl_xor(a1, b, 64);
        a8 += __shfl_xor(a8, b, 64);
        a9 += __shfl_xor(a9, b, 64);
        const float e = __shfl_xor(P, b, 64);
        P = (t & b) ? (e - P) : (e + P);   // WHT over lane bits
    }
    float* o = out + (size_t)n * NW;
    if (t == 0) { o[0] = a0; o[1] = a1; o[8] = a8; o[9] = a9; }
    if (t == 32) o[2] = P;   // wire 2 <- t bit 5
    if (t == 16) o[3] = P;   // wire 3 <- t bit 4
    if (t ==  8) o[4] = P;   // wire 4 <- t bit 3
    if (t ==  4) o[5] = P;   // wire 5 <- t bit 2
    if (t ==  2) o[6] = P;   // wire 6 <- t bit 1
    if (t ==  1) o[7] = P;   // wire 7 <- t bit 0
}

extern "C" void kernel_launch(void* const* d_in, const int* in_sizes, int n_in,
                              void* d_out, int out_size, void* d_ws, size_t ws_size,
                              hipStream_t stream) {
    const float* x   = (const float*)d_in[0];
    const float* rx0 = (const float*)d_in[1];
    const float* ry0 = (const float*)d_in[2];
    const float* ry1 = (const float*)d_in[3];
    float* out = (float*)d_out;
    const int nstates = in_sizes[0] >> 10;   // 4096
    qsa_main<<<nstates, 64, 0, stream>>>(x, rx0, ry0, ry1, out);
}

// Round 9
// 81.554 us; speedup vs baseline: 1.0161x; 1.0161x over previous
//
#include <hip/hip_runtime.h>

#define NW 10
typedef float f32x2 __attribute__((ext_vector_type(2)));

// ---- VOP3P packed fp32 helpers (R7-proven) ----
__device__ __forceinline__ f32x2 pk_mul(f32x2 a, f32x2 b) {
    f32x2 d;
    asm("v_pk_mul_f32 %0, %1, %2" : "=v"(d) : "v"(a), "v"(b));
    return d;
}
__device__ __forceinline__ f32x2 pk_fma(f32x2 a, f32x2 b, f32x2 c) {
    f32x2 d;
    asm("v_pk_fma_f32 %0, %1, %2, %3" : "=v"(d) : "v"(a), "v"(b), "v"(c));
    return d;
}
// d = a * swap2(b) + c   (swap folded into op_sel on src1)
__device__ __forceinline__ f32x2 pk_fma_sw1(f32x2 a, f32x2 b, f32x2 c) {
    f32x2 d;
    asm("v_pk_fma_f32 %0, %1, %2, %3 op_sel:[0,1,0] op_sel_hi:[1,0,1]"
        : "=v"(d) : "v"(a), "v"(b), "v"(c));
    return d;
}
__device__ __forceinline__ f32x2 sp2(float x)   { return f32x2{ x,  x}; }
__device__ __forceinline__ f32x2 sp2pm(float x) { return f32x2{ x, -x}; }
__device__ __forceinline__ f32x2 sp2mp(float x) { return f32x2{-x,  x}; }

// ---- DPP partner fetch (VALU pipe, no DS, no barrier) ----
// CTRL 0xB1 = quad_perm [1,0,3,2] (lane xor 1); 0x4E = [2,3,0,1] (lane xor 2).
template<int CTRL>
__device__ __forceinline__ f32x2 dpp2(f32x2 v) {
    f32x2 d;
    d.x = __int_as_float(__builtin_amdgcn_mov_dpp(__float_as_int(v.x), CTRL, 0xF, 0xF, true));
    d.y = __int_as_float(__builtin_amdgcn_mov_dpp(__float_as_int(v.y), CTRL, 0xF, 0xF, true));
    return d;
}

// CNOT-ring fused permutation (GF(2)-linear): psi_final[i] = psi_in[gperm(i)].
__device__ __forceinline__ int gperm(int v) {
    #pragma unroll
    for (int k = 9; k >= 0; --k) {
        const int cs = 9 - k;
        const int ts = 9 - ((k + 1) % NW);
        v ^= ((v >> cs) & 1) << ts;
    }
    return v;
}

// Two-level padded float index (R3-proven bank behavior, 16B-align preserved).
__device__ __forceinline__ int PF(int i) {
    return i + ((i >> 5) << 2) + ((i >> 8) << 3);
}
#define PBUF 1176

__device__ __forceinline__ float rl(float v, int lane) {
    return __int_as_float(__builtin_amdgcn_readlane(__float_as_int(v), lane));
}

// ---- complex gate [[a,b],[-conj(b),conj(a)]] between register pairs, dist D ----
template<int D>
__device__ __forceinline__ void cgv(f32x2* rf, f32x2* mf,
                                    float ar, float ai, float br, float bi) {
    const f32x2 sAr = sp2(ar),  sAi  = sp2(ai),  sAiN = sp2(-ai);
    const f32x2 sBr = sp2(br),  sBrN = sp2(-br);
    const f32x2 sBi = sp2(bi),  sBiN = sp2(-bi);
    #pragma unroll
    for (int base = 0; base < 8; base += 2 * D) {
        #pragma unroll
        for (int off = 0; off < D; ++off) {
            const int j0 = base + off, j1 = j0 + D;
            const f32x2 v0r = rf[j0], v0i = mf[j0];
            const f32x2 v1r = rf[j1], v1i = mf[j1];
            f32x2 t = pk_mul(sAr, v0r);
            t = pk_fma(sAiN, v0i, t); t = pk_fma(sBr, v1r, t);
            rf[j0] = pk_fma(sBiN, v1i, t);
            t = pk_mul(sAr, v0i);
            t = pk_fma(sAi, v0r, t);  t = pk_fma(sBr, v1i, t);
            mf[j0] = pk_fma(sBi, v1r, t);
            t = pk_mul(sAr, v1r);
            t = pk_fma(sAi, v1i, t);  t = pk_fma(sBrN, v0r, t);
            rf[j1] = pk_fma(sBiN, v0i, t);
            t = pk_mul(sAr, v1i);
            t = pk_fma(sAiN, v1r, t); t = pk_fma(sBrN, v0i, t);
            mf[j1] = pk_fma(sBi, v0r, t);
        }
    }
}

// complex gate WITHIN each f32x2 (R7-verified)
__device__ __forceinline__ void cgv0(f32x2* rf, f32x2* mf,
                                     float ar, float ai, float br, float bi) {
    const f32x2 sAr  = sp2(ar);
    const f32x2 sAiN = sp2mp(ai);
    const f32x2 sAiP = sp2pm(ai);
    const f32x2 sBrN = sp2pm(br);
    const f32x2 sBiN = sp2(-bi);
    const f32x2 sBi  = sp2(bi);
    #pragma unroll
    for (int j = 0; j < 8; ++j) {
        const f32x2 vr = rf[j], vi = mf[j];
        f32x2 t = pk_mul(sAr, vr);
        t = pk_fma(sAiN, vi, t);
        t = pk_fma_sw1(sBrN, vr, t);
        rf[j] = pk_fma_sw1(sBiN, vi, t);
        t = pk_mul(sAr, vi);
        t = pk_fma(sAiP, vr, t);
        t = pk_fma_sw1(sBrN, vi, t);
        mf[j] = pk_fma_sw1(sBi, vr, t);
    }
}

// complex gate on a LANE bit via DPP partner; sg = +1 (bit==0 side) / -1.
// own-side update: nr = ar*or - (sg*ai)*oi + (sg*br)*pr - bi*pi
//                  ni = ar*oi + (sg*ai)*or + (sg*br)*pi + bi*pr
template<int CTRL>
__device__ __forceinline__ void cgd(f32x2* rf, f32x2* mf, float sg,
                                    float ar, float ai, float br, float bi) {
    const f32x2 sAr   = sp2(ar);
    const f32x2 sAiS  = sp2(sg * ai);
    const f32x2 sAiSN = sp2(-sg * ai);
    const f32x2 sBrS  = sp2(sg * br);
    const f32x2 sBi   = sp2(bi);
    const f32x2 sBiN  = sp2(-bi);
    #pragma unroll
    for (int j = 0; j < 8; ++j) {
        const f32x2 orr = rf[j], oii = mf[j];
        const f32x2 prr = dpp2<CTRL>(orr), pii = dpp2<CTRL>(oii);
        f32x2 t = pk_mul(sAr, orr);
        t = pk_fma(sAiSN, oii, t);
        t = pk_fma(sBrS, prr, t);
        rf[j] = pk_fma(sBiN, pii, t);
        t = pk_mul(sAr, oii);
        t = pk_fma(sAiS, orr, t);
        t = pk_fma(sBrS, pii, t);
        mf[j] = pk_fma(sBi, prr, t);
    }
}

// real RY between register pairs, dist D
template<int D>
__device__ __forceinline__ void rgv(f32x2* rf, f32x2* mf, float c, float s) {
    const f32x2 sC = sp2(c), sS = sp2(s), sSN = sp2(-s);
    #pragma unroll
    for (int base = 0; base < 8; base += 2 * D) {
        #pragma unroll
        for (int off = 0; off < D; ++off) {
            const int j0 = base + off, j1 = j0 + D;
            const f32x2 v0r = rf[j0], v0i = mf[j0];
            const f32x2 v1r = rf[j1], v1i = mf[j1];
            rf[j0] = pk_fma(sSN, v1r, pk_mul(sC, v0r));
            mf[j0] = pk_fma(sSN, v1i, pk_mul(sC, v0i));
            rf[j1] = pk_fma(sC, v1r, pk_mul(sS, v0r));
            mf[j1] = pk_fma(sC, v1i, pk_mul(sS, v0i));
        }
    }
}

// real RY WITHIN each f32x2 (R7-verified)
__device__ __forceinline__ void rgv0(f32x2* rf, f32x2* mf, float c, float s) {
    const f32x2 sC = sp2(c), sSN = sp2mp(s);
    #pragma unroll
    for (int j = 0; j < 8; ++j) {
        const f32x2 vr = rf[j], vi = mf[j];
        rf[j] = pk_fma_sw1(sSN, vr, pk_mul(sC, vr));
        mf[j] = pk_fma_sw1(sSN, vi, pk_mul(sC, vi));
    }
}

// real RY on a LANE bit via DPP; own-side: n = c*o + (-sg*s)*p
template<int CTRL>
__device__ __forceinline__ void rgd(f32x2* rf, f32x2* mf, float sg, float c, float s) {
    const f32x2 sC = sp2(c), sS = sp2(-sg * s);
    #pragma unroll
    for (int j = 0; j < 8; ++j) {
        rf[j] = pk_fma(sS, dpp2<CTRL>(rf[j]), pk_mul(sC, rf[j]));
        mf[j] = pk_fma(sS, dpp2<CTRL>(mf[j]), pk_mul(sC, mf[j]));
    }
}

// One wave per block = per state. 16 amps/lane as 8 f32x2.
// L0: i = t<<4 | r          (r bits -> wires 9,8,7,6; lane bits t0..t5 -> wires 5..0)
// L1: i = r<<6 | (t&3)<<4 | (t>>2)
//                           (r bits -> wires 3,2,1,0; t0,t1 -> wires 5,4; t2..t5 -> wires 9..6)
__global__ __launch_bounds__(64) void qsa_main(
    const float* __restrict__ x,
    const float* __restrict__ rx0,
    const float* __restrict__ ry0,
    const float* __restrict__ ry1,
    float* __restrict__ out) {

    __shared__ __align__(16) float reb[PBUF];
    __shared__ __align__(16) float imb[PBUF];

    const int t = threadIdx.x;
    const int n = blockIdx.x;

    // ---- load row (L0): rf[j] = amps (16t+2j, 16t+2j+1) ----
    f32x2 rf[8], mf[8];
    const float* xr = x + ((size_t)n << 10) + (t << 4);
    #pragma unroll
    for (int k = 0; k < 4; ++k) {
        const float4 v = *reinterpret_cast<const float4*>(xr + 4 * k);
        rf[2*k]   = f32x2{v.x, v.y};
        rf[2*k+1] = f32x2{v.z, v.w};
    }

    // ---- per-wire coefficients in lanes 0..9 ----
    float car = 0.f, cai = 0.f, cbr = 0.f, cbi = 0.f, cc1 = 0.f, cs1 = 0.f;
    if (t < NW) {
        float sx, cx, sy0, cy0;
        sincosf(0.5f * rx0[t], &sx,  &cx);
        sincosf(0.5f * ry0[t], &sy0, &cy0);
        sincosf(0.5f * ry1[t], &cs1, &cc1);
        car =  cy0 * cx;  cai =  sy0 * sx;   // fused RY(ry0)*RX(rx0)
        cbr = -sy0 * cx;  cbi = -cy0 * sx;
    }

    // ---- normalization ----
    f32x2 ssv = {0.f, 0.f};
    #pragma unroll
    for (int j = 0; j < 8; ++j) ssv += rf[j] * rf[j];
    float ss = ssv.x + ssv.y;
    #pragma unroll
    for (int b = 32; b > 0; b >>= 1) ss += __shfl_xor(ss, b, 64);
    const float scale = 1.0f / fmaxf(sqrtf(ss), 1e-12f);

    // per-thread DPP gate signs: +1 on bit==0 side, -1 on bit==1 side
    const float sg1 = (t & 1) ? -1.f : 1.f;   // lane bit 0
    const float sg2 = (t & 2) ? -1.f : 1.f;   // lane bit 1

    // ========= layer 1 in L0: wires 9,8,7,6 (regs) + 5,4 (DPP) =========
    {   // wire 9 (within-pair): input real; fold normalization (R7-verified)
        const float ar = rl(car,9), ai = rl(cai,9), br = rl(cbr,9), bi = rl(cbi,9);
        const f32x2 sSc  = sp2(scale);
        const f32x2 sAr  = sp2(ar);
        const f32x2 sAiP = sp2pm(ai);
        const f32x2 sBrN = sp2pm(br);
        const f32x2 sBi  = sp2(bi);
        #pragma unroll
        for (int j = 0; j < 8; ++j) {
            const f32x2 v = pk_mul(sSc, rf[j]);
            rf[j] = pk_fma_sw1(sBrN, v, pk_mul(sAr, v));
            mf[j] = pk_fma_sw1(sBi,  v, pk_mul(sAiP, v));
        }
    }
    cgv<1>(rf, mf, rl(car,8), rl(cai,8), rl(cbr,8), rl(cbi,8));        // wire 8
    cgv<2>(rf, mf, rl(car,7), rl(cai,7), rl(cbr,7), rl(cbi,7));        // wire 7
    cgv<4>(rf, mf, rl(car,6), rl(cai,6), rl(cbr,6), rl(cbi,6));        // wire 6
    cgd<0xB1>(rf, mf, sg1, rl(car,5), rl(cai,5), rl(cbr,5), rl(cbi,5)); // wire 5
    cgd<0x4E>(rf, mf, sg2, rl(car,4), rl(cai,4), rl(cbr,4), rl(cbi,4)); // wire 4

    // T1: write L0 (b128), read L1 (b32)
    #pragma unroll
    for (int k = 0; k < 4; ++k) {
        const int p = PF((t << 4) + 4 * k);
        *reinterpret_cast<float4*>(&reb[p]) =
            make_float4(rf[2*k].x, rf[2*k].y, rf[2*k+1].x, rf[2*k+1].y);
        *reinterpret_cast<float4*>(&imb[p]) =
            make_float4(mf[2*k].x, mf[2*k].y, mf[2*k+1].x, mf[2*k+1].y);
    }
    __syncthreads();
    const int b1 = ((t & 3) << 4) | (t >> 2);
    #pragma unroll
    for (int j = 0; j < 8; ++j) {
        const int p0 = PF(((2*j) << 6) | b1), p1 = PF(((2*j+1) << 6) | b1);
        rf[j] = f32x2{reb[p0], reb[p1]};
        mf[j] = f32x2{imb[p0], imb[p1]};
    }

    // ========= layer 1 in L1: wires 3,2,1,0 (regs) =========
    cgv0  (rf, mf, rl(car,3), rl(cai,3), rl(cbr,3), rl(cbi,3));   // wire 3
    cgv<1>(rf, mf, rl(car,2), rl(cai,2), rl(cbr,2), rl(cbi,2));   // wire 2
    cgv<2>(rf, mf, rl(car,1), rl(cai,1), rl(cbr,1), rl(cbi,1));   // wire 1
    cgv<4>(rf, mf, rl(car,0), rl(cai,0), rl(cbr,0), rl(cbi,0));   // wire 0

    // T2: CNOT-ring gather (write L1 slots, read gperm addresses, stay L1)
    __syncthreads();
    #pragma unroll
    for (int j = 0; j < 8; ++j) {
        const int p0 = PF(((2*j) << 6) | b1), p1 = PF(((2*j+1) << 6) | b1);
        reb[p0] = rf[j].x; reb[p1] = rf[j].y;
        imb[p0] = mf[j].x; imb[p1] = mf[j].y;
    }
    __syncthreads();
    {
        const int gb = gperm(b1);
        #pragma unroll
        for (int j = 0; j < 8; ++j) {
            const int p0 = PF(gperm((2*j) << 6) ^ gb);     // gperm(const) folds
            const int p1 = PF(gperm((2*j+1) << 6) ^ gb);
            rf[j] = f32x2{reb[p0], reb[p1]};
            mf[j] = f32x2{imb[p0], imb[p1]};
        }
    }

    // ========= layer 2 in L1: wires 0,1,2,3 (regs) + 4,5 (DPP) =========
    rgv<4>(rf, mf, rl(cc1,0), rl(cs1,0));            // wire 0
    rgv<2>(rf, mf, rl(cc1,1), rl(cs1,1));            // wire 1
    rgv<1>(rf, mf, rl(cc1,2), rl(cs1,2));            // wire 2
    rgv0  (rf, mf, rl(cc1,3), rl(cs1,3));            // wire 3
    rgd<0x4E>(rf, mf, sg2, rl(cc1,4), rl(cs1,4));    // wire 4 (lane bit 1)
    rgd<0xB1>(rf, mf, sg1, rl(cc1,5), rl(cs1,5));    // wire 5 (lane bit 0)

    // T3: write L1 slots, read L0 (b128)
    __syncthreads();
    #pragma unroll
    for (int j = 0; j < 8; ++j) {
        const int p0 = PF(((2*j) << 6) | b1), p1 = PF(((2*j+1) << 6) | b1);
        reb[p0] = rf[j].x; reb[p1] = rf[j].y;
        imb[p0] = mf[j].x; imb[p1] = mf[j].y;
    }
    __syncthreads();
    #pragma unroll
    for (int k = 0; k < 4; ++k) {
        const int p = PF((t << 4) + 4 * k);
        const float4 qr = *reinterpret_cast<const float4*>(&reb[p]);
        const float4 qi = *reinterpret_cast<const float4*>(&imb[p]);
        rf[2*k] = f32x2{qr.x, qr.y}; rf[2*k+1] = f32x2{qr.z, qr.w};
        mf[2*k] = f32x2{qi.x, qi.y}; mf[2*k+1] = f32x2{qi.z, qi.w};
    }

    // ========= layer 2 in L0: wires 6,7,8,9 (regs) =========
    rgv<4>(rf, mf, rl(cc1,6), rl(cs1,6));   // wire 6
    rgv<2>(rf, mf, rl(cc1,7), rl(cs1,7));   // wire 7
    rgv<1>(rf, mf, rl(cc1,8), rl(cs1,8));   // wire 8
    rgv0  (rf, mf, rl(cc1,9), rl(cs1,9));   // wire 9

    // ---- Z expectations in L0 (i = t<<4 | r) ----
    // wires 9,8,7,6 <- r bits 0..3; wires 5..0 <- lane bits t0..t5 (WHT)
    f32x2 accP = {0,0}, acc9 = {0,0}, acc8 = {0,0}, acc7 = {0,0}, acc6 = {0,0};
    const f32x2 pm = {1.f, -1.f};
    #pragma unroll
    for (int j = 0; j < 8; ++j) {
        const f32x2 p = rf[j]*rf[j] + mf[j]*mf[j];
        accP += p;
        acc9 += pm * p;
        if (j & 1) acc8 -= p; else acc8 += p;
        if (j & 2) acc7 -= p; else acc7 += p;
        if (j & 4) acc6 -= p; else acc6 += p;
    }
    float P  = accP.x + accP.y;
    float a9 = acc9.x + acc9.y;
    float a8 = acc8.x + acc8.y;
    float a7 = acc7.x + acc7.y;
    float a6 = acc6.x + acc6.y;
    #pragma unroll
    for (int b = 1; b < 64; b <<= 1) {
        a6 += __shfl_xor(a6, b, 64);
        a7 += __shfl_xor(a7, b, 64);
        a8 += __shfl_xor(a8, b, 64);
        a9 += __shfl_xor(a9, b, 64);
        const float e = __shfl_xor(P, b, 64);
        P = (t & b) ? (e - P) : (e + P);   // WHT over lane bits
    }
    float* o = out + (size_t)n * NW;
    if (t == 0) { o[6] = a6; o[7] = a7; o[8] = a8; o[9] = a9; }
    if (t ==  1) o[5] = P;   // wire 5 <- t bit 0
    if (t ==  2) o[4] = P;   // wire 4 <- t bit 1
    if (t ==  4) o[3] = P;   // wire 3 <- t bit 2
    if (t ==  8) o[2] = P;   // wire 2 <- t bit 3
    if (t == 16) o[1] = P;   // wire 1 <- t bit 4
    if (t == 32) o[0] = P;   // wire 0 <- t bit 5
}

extern "C" void kernel_launch(void* const* d_in, const int* in_sizes, int n_in,
                              void* d_out, int out_size, void* d_ws, size_t ws_size,
                              hipStream_t stream) {
    const float* x   = (const float*)d_in[0];
    const float* rx0 = (const float*)d_in[1];
    const float* ry0 = (const float*)d_in[2];
    const float* ry1 = (const float*)d_in[3];
    float* out = (float*)d_out;
    const int nstates = in_sizes[0] >> 10;   // 4096
    qsa_main<<<nstates, 64, 0, stream>>>(x, rx0, ry0, ry1, out);
}